// Round 8
// baseline (3795.517 us; speedup 1.0000x reference)
//
#include <hip/hip_runtime.h>
#include <stdint.h>

// Problem dims
#define S_ 256
#define B_ 32
#define H_ 256
#define G4_ 1024   // 4*H

typedef short bf16x8 __attribute__((ext_vector_type(8)));
typedef float f32x4  __attribute__((ext_vector_type(4)));

__device__ __forceinline__ unsigned f2bf(float f){
  unsigned u = __float_as_uint(f);
  return (u + 0x7fffu + ((u >> 16) & 1u)) >> 16;   // RNE to bf16
}
__device__ __forceinline__ float bfl(unsigned u){ return __uint_as_float(u << 16); }
__device__ __forceinline__ float bfh(unsigned u){ return __uint_as_float(u & 0xffff0000u); }
__device__ __forceinline__ float sigf(float x){ return 1.0f / (1.0f + __expf(-x)); }
__device__ __forceinline__ float thf(float x){
  x = fminf(fmaxf(x, -15.0f), 15.0f);
  float e = __expf(2.0f * x);
  return (e - 1.0f) / (e + 1.0f);
}

// ---------------- prep: embedding gather -> bf16 x [8192][320]
__global__ __launch_bounds__(320) void k_prep(const int* __restrict__ words,
                                              const float* __restrict__ emb,
                                              unsigned short* __restrict__ x){
  int row = blockIdx.x;            // s*32+b
  int e = threadIdx.x;             // 0..319
  int w = words[row];
  x[row * 320 + e] = (e < 300) ? (unsigned short)f2bf(emb[w * 300 + e]) : 0;
}

// ---------------- pack weights to bf16 (zero-padded K)
__global__ __launch_bounds__(256) void k_packw(
    const float* __restrict__ w0f, const float* __restrict__ w0b,
    const float* __restrict__ w1f, const float* __restrict__ w1b,
    const float* __restrict__ fw,
    unsigned short* __restrict__ wb0f, unsigned short* __restrict__ wb0b,
    unsigned short* __restrict__ wb1f, unsigned short* __restrict__ wb1b,
    unsigned short* __restrict__ fcwb){
  int r = blockIdx.x, tid = threadIdx.x;
  if (r < 2048){
    int rr = r & 1023;
    const float* src = (r < 1024) ? w0f : w0b;
    unsigned short* dst = (r < 1024) ? wb0f : wb0b;
    for (int e = tid; e < 320; e += 256)
      dst[rr * 320 + e] = (e < 300) ? (unsigned short)f2bf(src[rr * 300 + e]) : 0;
  } else if (r < 4096){
    int rr = r & 1023;
    const float* src = (r < 3072) ? w1f : w1b;
    unsigned short* dst = (r < 3072) ? wb1f : wb1b;
    for (int e = tid; e < 512; e += 256)
      dst[rr * 512 + e] = (unsigned short)f2bf(src[rr * 512 + e]);
  } else {
    int rr = r - 4096;
    for (int e = tid; e < 512; e += 256)
      fcwb[rr * 512 + e] = (unsigned short)f2bf(fw[rr * 512 + e]);
  }
}

// ---------------- bf16 MFMA GEMM (both dirs via blockIdx.z)
// Output layout CHANGED: C is transposed, Gt[col][8192] (col = gate index,
// row = s*32+b). Epilogue per thread: one float4 store (4 consecutive rows of
// one column) -- better coalescing than the old 4 scattered dwords, and lets
// the LSTM kernel acc-init with contiguous float4 loads.
__global__ __launch_bounds__(256) void k_gemm_bf2(
    const unsigned short* __restrict__ A, int lda, int nSteps,
    const unsigned short* __restrict__ Bf, const unsigned short* __restrict__ Bb,
    const float* __restrict__ b1f, const float* __restrict__ b2f,
    const float* __restrict__ b1b, const float* __restrict__ b2b,
    float* __restrict__ Cf, float* __restrict__ Cb){
  const int z = blockIdx.z;
  const unsigned short* __restrict__ B = z ? Bb : Bf;
  const float* __restrict__ bias1 = z ? b1b : b1f;
  const float* __restrict__ bias2 = z ? b2b : b2f;
  float* __restrict__ C = z ? Cb : Cf;

  __shared__ __align__(16) unsigned As[64 * 20];
  __shared__ __align__(16) unsigned Bs[128 * 20];
  const int tid = threadIdx.x;
  const int w = tid >> 6, lane = tid & 63;
  const int quad = lane >> 4, coln = lane & 15;
  const int m0 = blockIdx.y * 64, n0 = blockIdx.x * 128;

  f32x4 acc[8];
  #pragma unroll
  for (int i = 0; i < 8; ++i){ acc[i][0]=0.f; acc[i][1]=0.f; acc[i][2]=0.f; acc[i][3]=0.f; }

  for (int kt = 0; kt < nSteps; ++kt){
    int k0 = kt * 32;
    __syncthreads();
    {
      int row = tid >> 2, part = tid & 3;
      *(uint4*)&As[row * 20 + part * 4] =
          *(const uint4*)(A + (size_t)(m0 + row) * lda + k0 + part * 8);
    }
    #pragma unroll
    for (int i = 0; i < 2; ++i){
      int idx = tid + 256 * i;
      int row = idx >> 2, part = idx & 3;
      *(uint4*)&Bs[row * 20 + part * 4] =
          *(const uint4*)(B + (size_t)(n0 + row) * lda + k0 + part * 8);
    }
    __syncthreads();
    union { uint4 q; bf16x8 v; } au;
    au.q = *(const uint4*)&As[(w * 16 + coln) * 20 + quad * 4];
    #pragma unroll
    for (int nt = 0; nt < 8; ++nt){
      union { uint4 q; bf16x8 v; } bu;
      bu.q = *(const uint4*)&Bs[(nt * 16 + coln) * 20 + quad * 4];
      acc[nt] = __builtin_amdgcn_mfma_f32_16x16x32_bf16(au.v, bu.v, acc[nt], 0, 0, 0);
    }
  }
  #pragma unroll
  for (int nt = 0; nt < 8; ++nt){
    int col = n0 + nt * 16 + coln;
    float bs = bias1[col] + bias2[col];
    float4 st;
    st.x = acc[nt][0] + bs; st.y = acc[nt][1] + bs;
    st.z = acc[nt][2] + bs; st.w = acc[nt][3] + bs;
    *(float4*)&C[(size_t)col * 8192 + m0 + w * 16 + quad * 4] = st;
  }
}

// ---------------- MFMA LSTM recurrence: one WG per (dir, bh) -- ZERO
// cross-workgroup communication. 512 threads = 8 waves (2/SIMD, 256-VGPR cap).
// Weights [1024][256] bf16 partition:
//   - K-slices 0..5, all 8 tiles:      registers Wr[48]  (192 VGPR)
//   - K-slices 6..7, tiles g=0..2:     static LDS (96 KB, fragment-order)
//   - K-slices 6..7, tiles g=3 (o):    registers Wr2[4]  (16 VGPR)
// Total static LDS = 96K + 16.5K = 115.2 KB (<= the 128 KiB envelope verified
// in plain HIP on gfx950). acc initialized directly from transposed G
// (contiguous float4 loads). h exchange = LDS double-buffer + ONE
// __syncthreads per step. Fragment layouts identical to the verified R0 kernel.
__global__ __launch_bounds__(512, 2) void k_lstm2(
    const float* __restrict__ Gtf, const float* __restrict__ Gtb,  // [1024][8192]
    const float* __restrict__ Whf, const float* __restrict__ Whb,
    unsigned short* __restrict__ Hout)         // [S][32][512] bf16
{
  __shared__ __align__(16) unsigned wlds[24576];   // 96 KB
  __shared__ __align__(16) unsigned hx[2 * 2112];  // 16.5 KB

  const int dir = blockIdx.x >> 1, bh = blockIdx.x & 1;
  const float* __restrict__ G  = dir ? Gtb : Gtf;
  const float* __restrict__ Wh = dir ? Whb : Whf;
  const int tid  = threadIdx.x;              // 0..511
  const int w    = tid >> 6;                 // wave 0..7 -> h-units [w*32, w*32+32)
  const int lane = tid & 63;
  const int quad = lane >> 4, coln = lane & 15;
  const int mrw  = quad << 2;

  // ---- prologue: weights -> regs / LDS
  bf16x8 Wr[48];                             // [tile = g*2+p][ks 0..5]
  bf16x8 Wr2[4];                             // g=3 tiles, ks 6..7: [p*2 + (ks-6)]
  #pragma unroll
  for (int g = 0; g < 4; ++g){
    #pragma unroll
    for (int p = 0; p < 2; ++p){
      const int col = g * 256 + (w << 5) + (p << 4) + coln;
      const float* wbase = Wh + (size_t)col * 256;
      #pragma unroll
      for (int ks = 0; ks < 8; ++ks){
        const float* wp = wbase + ks * 32 + quad * 8;
        float4 a = *(const float4*)wp;
        float4 b = *(const float4*)(wp + 4);
        union { unsigned u[4]; bf16x8 v; uint4 q; } tu;
        tu.u[0] = f2bf(a.x) | (f2bf(a.y) << 16);
        tu.u[1] = f2bf(a.z) | (f2bf(a.w) << 16);
        tu.u[2] = f2bf(b.x) | (f2bf(b.y) << 16);
        tu.u[3] = f2bf(b.z) | (f2bf(b.w) << 16);
        if (ks < 6){
          Wr[(g * 2 + p) * 6 + ks] = tu.v;
        } else if (g < 3){
          // per (wave,tile,slice): 1KB block, lane-consecutive 16B (conflict-free)
          *(uint4*)&wlds[((w * 6 + (g * 2 + p)) * 2 + (ks - 6)) * 256
                         + (lane << 2)] = tu.q;
        } else {
          Wr2[p * 2 + (ks - 6)] = tu.v;
        }
      }
    }
  }
  __syncthreads();

  float cst[2][4];
  #pragma unroll
  for (int p = 0; p < 2; ++p)
    #pragma unroll
    for (int r = 0; r < 4; ++r) cst[p][r] = 0.f;

  for (int t = 0; t < 256; ++t){
    const int s = dir ? (255 - t) : t;
    const int r0 = s * 32 + bh * 16 + mrw;
    const unsigned* hxr = hx + (t & 1) * 2112;
    unsigned*       hxw = hx + ((t + 1) & 1) * 2112;

    #pragma unroll
    for (int p = 0; p < 2; ++p){
      // acc init directly from transposed G: 4 contiguous float4 loads
      f32x4 acc[4];
      #pragma unroll
      for (int g = 0; g < 4; ++g){
        const int col = g * 256 + (w << 5) + (p << 4) + coln;
        acc[g] = *(const f32x4*)(G + (size_t)col * 8192 + r0);
      }
      if (t > 0){
        #pragma unroll
        for (int ks = 0; ks < 6; ++ks){
          union { uint4 q; bf16x8 v; } hf;
          hf.q = *(const uint4*)&hxr[coln * 132 + ks * 16 + quad * 4];
          #pragma unroll
          for (int g = 0; g < 4; ++g)
            acc[g] = __builtin_amdgcn_mfma_f32_16x16x32_bf16(
                hf.v, Wr[(g * 2 + p) * 6 + ks], acc[g], 0, 0, 0);
        }
        #pragma unroll
        for (int ks = 6; ks < 8; ++ks){
          union { uint4 q; bf16x8 v; } hf;
          hf.q = *(const uint4*)&hxr[coln * 132 + ks * 16 + quad * 4];
          #pragma unroll
          for (int g = 0; g < 3; ++g){
            union { uint4 q; bf16x8 v; } wf;
            wf.q = *(const uint4*)&wlds[((w * 6 + (g * 2 + p)) * 2 + (ks - 6)) * 256
                                        + (lane << 2)];
            acc[g] = __builtin_amdgcn_mfma_f32_16x16x32_bf16(
                hf.v, wf.v, acc[g], 0, 0, 0);
          }
          acc[3] = __builtin_amdgcn_mfma_f32_16x16x32_bf16(
              hf.v, Wr2[p * 2 + (ks - 6)], acc[3], 0, 0, 0);
        }
      }
      // activations + h publish (LDS only) + Hout
      #pragma unroll
      for (int reg = 0; reg < 4; ++reg){
        float gi = sigf(acc[0][reg]);
        float gf = sigf(acc[1][reg]);
        float gg = thf (acc[2][reg]);
        float go = sigf(acc[3][reg]);
        float cv = gf * cst[p][reg] + gi * gg;
        cst[p][reg] = cv;
        float hv = go * thf(cv);
        unsigned hb16 = f2bf(hv);
        unsigned other = (unsigned)__shfl_xor((int)hb16, 1);
        if (!(coln & 1))
          hxw[(mrw + reg) * 132 + ((w << 4) + (p << 3) + (coln >> 1))] =
              hb16 | (other << 16);
        Hout[(size_t)(s * 32 + bh * 16 + mrw + reg) * 512 + dir * 256
             + (w << 5) + (p << 4) + coln] = (unsigned short)hb16;
      }
    }
    __syncthreads();   // hx[next] complete before t+1 reads it
  }
}

// ---------------- FC: em[row][t] = h1[row][:512].fcw[t][:512] + fcb[t]  (bf16 in)
__global__ __launch_bounds__(64) void k_fc(const unsigned short* __restrict__ h1,
                                           const unsigned short* __restrict__ fw,
                                           const float* __restrict__ fb,
                                           float* __restrict__ em){
  int row = blockIdx.x;
  int lane = threadIdx.x;
  int tag = lane & 31, half = lane >> 5;
  const uint4* hp = (const uint4*)(h1 + (size_t)row * 512 + half * 256);
  const uint4* wp = (const uint4*)(fw + (size_t)tag * 512 + half * 256);
  float acc = 0.0f;
  #pragma unroll 8
  for (int i = 0; i < 32; ++i){
    uint4 h = hp[i], v = wp[i];
    acc += bfl(h.x) * bfl(v.x) + bfh(h.x) * bfh(v.x)
         + bfl(h.y) * bfl(v.y) + bfh(h.y) * bfh(v.y)
         + bfl(h.z) * bfl(v.z) + bfh(h.z) * bfh(v.z)
         + bfl(h.w) * bfl(v.w) + bfh(h.w) * bfh(v.w);
  }
  acc += __shfl_down(acc, 32);
  if (half == 0) em[row * 32 + tag] = acc + fb[tag];
}

// ---------------- CRF: blocks 0..31 viterbi, 32..63 loss
__global__ __launch_bounds__(64) void k_crf(const float* __restrict__ em,
                                            const int* __restrict__ tags,
                                            const float* __restrict__ start,
                                            const float* __restrict__ trans,
                                            const float* __restrict__ endv,
                                            int* __restrict__ path,
                                            float* __restrict__ lossb){
  __shared__ float tr[1024];
  __shared__ float sc[32], sc2[32];
  __shared__ unsigned char bp[255][32];
  int b = blockIdx.x & 31, mode = blockIdx.x >> 5;
  int t = threadIdx.x;
  for (int i = t; i < 1024; i += 64) tr[i] = trans[i];
  if (t < 32) sc[t] = start[t] + em[b * 32 + t];
  __syncthreads();
  if (mode == 0){
    for (int s = 1; s < 256; ++s){
      if (t < 32){
        float best = -1e30f; int bi = 0;
        for (int p = 0; p < 32; ++p){
          float v = sc[p] + tr[p * 32 + t];
          if (v > best){ best = v; bi = p; }
        }
        sc2[t] = best + em[(s * 32 + b) * 32 + t];
        bp[s - 1][t] = (unsigned char)bi;
      }
      __syncthreads();
      if (t < 32) sc[t] = sc2[t];
      __syncthreads();
    }
    if (t == 0){
      float best = -1e30f; int bi = 0;
      for (int p = 0; p < 32; ++p){
        float v = sc[p] + endv[p];
        if (v > best){ best = v; bi = p; }
      }
      int cur = bi;
      path[255 * 32 + b] = cur;
      for (int s = 254; s >= 0; --s){
        cur = bp[s][cur];
        path[s * 32 + b] = cur;
      }
    }
  } else {
    for (int s = 1; s < 256; ++s){
      if (t < 32){
        float m = -1e30f;
        for (int p = 0; p < 32; ++p){ float v = sc[p] + tr[p * 32 + t]; m = fmaxf(m, v); }
        float ss = 0.0f;
        for (int p = 0; p < 32; ++p){ ss += __expf(sc[p] + tr[p * 32 + t] - m); }
        sc2[t] = m + __logf(ss) + em[(s * 32 + b) * 32 + t];
      }
      __syncthreads();
      if (t < 32) sc[t] = sc2[t];
      __syncthreads();
    }
    float nsum = 0.0f;
    for (int s = t; s < 256; s += 64){
      int tg = tags[s * 32 + b];
      nsum += em[(s * 32 + b) * 32 + tg];
      if (s == 0) nsum += start[tg];
      else        nsum += tr[tags[(s - 1) * 32 + b] * 32 + tg];
      if (s == 255) nsum += endv[tg];
    }
    #pragma unroll
    for (int off = 32; off >= 1; off >>= 1) nsum += __shfl_down(nsum, off);
    if (t == 0){
      float m = -1e30f;
      for (int p = 0; p < 32; ++p) m = fmaxf(m, sc[p] + endv[p]);
      float ss = 0.0f;
      for (int p = 0; p < 32; ++p) ss += __expf(sc[p] + endv[p] - m);
      lossb[b] = m + __logf(ss) - nsum;
    }
  }
}

// Sum per-batch losses; write as FLOAT (d_out read back as float32).
__global__ __launch_bounds__(64) void k_final(const float* __restrict__ lossb,
                                              float* __restrict__ outp){
  float v = (threadIdx.x < 32) ? lossb[threadIdx.x] : 0.0f;
  #pragma unroll
  for (int off = 32; off >= 1; off >>= 1) v += __shfl_down(v, off);
  if (threadIdx.x == 0) outp[0] = v;
}

extern "C" void kernel_launch(void* const* d_in, const int* in_sizes, int n_in,
                              void* d_out, int out_size, void* d_ws, size_t ws_size,
                              hipStream_t stream){
  const int*   words  = (const int*)d_in[0];
  const int*   tags   = (const int*)d_in[2];
  const float* emb    = (const float*)d_in[3];
  const float* fcw    = (const float*)d_in[4];
  const float* fcb    = (const float*)d_in[5];
  const float* cstart = (const float*)d_in[6];
  const float* cend   = (const float*)d_in[7];
  const float* ctrans = (const float*)d_in[8];
  const float* w_ih[4] = {(const float*)d_in[9],  (const float*)d_in[13],
                          (const float*)d_in[17], (const float*)d_in[21]};
  const float* w_hh[4] = {(const float*)d_in[10], (const float*)d_in[14],
                          (const float*)d_in[18], (const float*)d_in[22]};
  const float* b_ih[4] = {(const float*)d_in[11], (const float*)d_in[15],
                          (const float*)d_in[19], (const float*)d_in[23]};
  const float* b_hh[4] = {(const float*)d_in[12], (const float*)d_in[16],
                          (const float*)d_in[20], (const float*)d_in[24]};

  char* base = (char*)d_ws;
  unsigned short* x    = (unsigned short*)base;                 // 5,242,880 B
  float* Gf            = (float*)(base + 5242880);              // 33,554,432 B (Gt layout)
  float* Gb            = (float*)(base + 38797312);             // 33,554,432 B (Gt layout)
  unsigned short* h0   = (unsigned short*)(base + 72351744);    // 8,388,608 B
  unsigned short* h1   = (unsigned short*)(base + 80740352);    // 8,388,608 B
  unsigned short* wb0f = (unsigned short*)(base + 89128960);    // 655,360 B
  unsigned short* wb0b = (unsigned short*)(base + 89784320);    // 655,360 B
  unsigned short* wb1f = (unsigned short*)(base + 90439680);    // 1,048,576 B
  unsigned short* wb1b = (unsigned short*)(base + 91488256);    // 1,048,576 B
  unsigned short* fcwb = (unsigned short*)(base + 92536832);    // 32,768 B
  float* lossb         = (float*)(base + 92569600);             // 128 B
  float* em            = Gf;                        // overlay: Gf dead after L1 lstm

  k_prep<<<8192, 320, 0, stream>>>(words, emb, x);
  k_packw<<<4128, 256, 0, stream>>>(w_ih[0], w_ih[1], w_ih[2], w_ih[3], fcw,
                                    wb0f, wb0b, wb1f, wb1b, fcwb);

  // layer 0 input projections (K padded to 320), both dirs in one launch
  k_gemm_bf2<<<dim3(8, 128, 2), 256, 0, stream>>>(x, 320, 10, wb0f, wb0b,
                                                  b_ih[0], b_hh[0], b_ih[1], b_hh[1],
                                                  Gf, Gb);
  k_lstm2<<<4, 512, 0, stream>>>(Gf, Gb, w_hh[0], w_hh[1], h0);

  // layer 1 input projections (K=512)
  k_gemm_bf2<<<dim3(8, 128, 2), 256, 0, stream>>>(h0, 512, 16, wb1f, wb1b,
                                                  b_ih[2], b_hh[2], b_ih[3], b_hh[3],
                                                  Gf, Gb);
  k_lstm2<<<4, 512, 0, stream>>>(Gf, Gb, w_hh[2], w_hh[3], h1);

  k_fc<<<8192, 64, 0, stream>>>(h1, fcwb, fcb, em);

  k_crf<<<64, 64, 0, stream>>>(em, tags, cstart, ctrans, cend, (int*)d_out, lossb);
  k_final<<<1, 64, 0, stream>>>(lossb, ((float*)d_out) + (out_size - 1));
}

// Round 9
// 1487.345 us; speedup vs baseline: 2.5519x; 2.5519x over previous
//
#include <hip/hip_runtime.h>
#include <stdint.h>

// Problem dims
#define S_ 256
#define B_ 32
#define H_ 256
#define G4_ 1024   // 4*H
#define HXW (16*132)

typedef short bf16x8 __attribute__((ext_vector_type(8)));
typedef float f32x4  __attribute__((ext_vector_type(4)));

__device__ __forceinline__ unsigned f2bf(float f){
  unsigned u = __float_as_uint(f);
  return (u + 0x7fffu + ((u >> 16) & 1u)) >> 16;   // RNE to bf16
}
__device__ __forceinline__ float bfl(unsigned u){ return __uint_as_float(u << 16); }
__device__ __forceinline__ float bfh(unsigned u){ return __uint_as_float(u & 0xffff0000u); }
__device__ __forceinline__ float sigf(float x){ return 1.0f / (1.0f + __expf(-x)); }
__device__ __forceinline__ float thf(float x){
  x = fminf(fmaxf(x, -15.0f), 15.0f);
  float e = __expf(2.0f * x);
  return (e - 1.0f) / (e + 1.0f);
}

// valid iff both 16b halves have bit14 set (|h|<=1 => raw bf16 bit14 clear)
__device__ __forceinline__ int hval_ok(unsigned long long v){
  return (((unsigned)v & (unsigned)(v >> 32)) & 0x40004000u) == 0x40004000u;
}

// ---------------- prep: embedding gather -> bf16 x [8192][320], zero L0 hbuf
__global__ __launch_bounds__(320) void k_prep(const int* __restrict__ words,
                                              const float* __restrict__ emb,
                                              unsigned short* __restrict__ x,
                                              unsigned* __restrict__ hbuf0){
  int row = blockIdx.x;            // s*32+b
  int e = threadIdx.x;             // 0..319
  int w = words[row];
  x[row * 320 + e] = (e < 300) ? (unsigned short)f2bf(emb[w * 300 + e]) : 0;
  if (e < 256) hbuf0[row * 256 + e] = 0;   // 8192*256 uints = 8 MB
}

// ---------------- pack weights to bf16 (zero-padded K)
__global__ __launch_bounds__(256) void k_packw(
    const float* __restrict__ w0f, const float* __restrict__ w0b,
    const float* __restrict__ w1f, const float* __restrict__ w1b,
    const float* __restrict__ fw,
    unsigned short* __restrict__ wb0f, unsigned short* __restrict__ wb0b,
    unsigned short* __restrict__ wb1f, unsigned short* __restrict__ wb1b,
    unsigned short* __restrict__ fcwb){
  int r = blockIdx.x, tid = threadIdx.x;
  if (r < 2048){
    int rr = r & 1023;
    const float* src = (r < 1024) ? w0f : w0b;
    unsigned short* dst = (r < 1024) ? wb0f : wb0b;
    for (int e = tid; e < 320; e += 256)
      dst[rr * 320 + e] = (e < 300) ? (unsigned short)f2bf(src[rr * 300 + e]) : 0;
  } else if (r < 4096){
    int rr = r & 1023;
    const float* src = (r < 3072) ? w1f : w1b;
    unsigned short* dst = (r < 3072) ? wb1f : wb1b;
    for (int e = tid; e < 512; e += 256)
      dst[rr * 512 + e] = (unsigned short)f2bf(src[rr * 512 + e]);
  } else {
    int rr = r - 4096;
    for (int e = tid; e < 512; e += 256)
      fcwb[rr * 512 + e] = (unsigned short)f2bf(fw[rr * 512 + e]);
  }
}

// ---------------- bf16 MFMA GEMM (both dirs via blockIdx.z) -- R0 verified
__global__ __launch_bounds__(256) void k_gemm_bf2(
    const unsigned short* __restrict__ A, int lda, int nSteps,
    const unsigned short* __restrict__ Bf, const unsigned short* __restrict__ Bb,
    const float* __restrict__ b1f, const float* __restrict__ b2f,
    const float* __restrict__ b1b, const float* __restrict__ b2b,
    float* __restrict__ Cf, float* __restrict__ Cb){
  const int z = blockIdx.z;
  const unsigned short* __restrict__ B = z ? Bb : Bf;
  const float* __restrict__ bias1 = z ? b1b : b1f;
  const float* __restrict__ bias2 = z ? b2b : b2f;
  float* __restrict__ C = z ? Cb : Cf;

  __shared__ __align__(16) unsigned As[64 * 20];
  __shared__ __align__(16) unsigned Bs[128 * 20];
  const int tid = threadIdx.x;
  const int w = tid >> 6, lane = tid & 63;
  const int quad = lane >> 4, coln = lane & 15;
  const int m0 = blockIdx.y * 64, n0 = blockIdx.x * 128;

  f32x4 acc[8];
  #pragma unroll
  for (int i = 0; i < 8; ++i){ acc[i][0]=0.f; acc[i][1]=0.f; acc[i][2]=0.f; acc[i][3]=0.f; }

  for (int kt = 0; kt < nSteps; ++kt){
    int k0 = kt * 32;
    __syncthreads();
    {
      int row = tid >> 2, part = tid & 3;
      *(uint4*)&As[row * 20 + part * 4] =
          *(const uint4*)(A + (size_t)(m0 + row) * lda + k0 + part * 8);
    }
    #pragma unroll
    for (int i = 0; i < 2; ++i){
      int idx = tid + 256 * i;
      int row = idx >> 2, part = idx & 3;
      *(uint4*)&Bs[row * 20 + part * 4] =
          *(const uint4*)(B + (size_t)(n0 + row) * lda + k0 + part * 8);
    }
    __syncthreads();
    union { uint4 q; bf16x8 v; } au;
    au.q = *(const uint4*)&As[(w * 16 + coln) * 20 + quad * 4];
    #pragma unroll
    for (int nt = 0; nt < 8; ++nt){
      union { uint4 q; bf16x8 v; } bu;
      bu.q = *(const uint4*)&Bs[(nt * 16 + coln) * 20 + quad * 4];
      acc[nt] = __builtin_amdgcn_mfma_f32_16x16x32_bf16(au.v, bu.v, acc[nt], 0, 0, 0);
    }
  }
  #pragma unroll
  for (int nt = 0; nt < 8; ++nt){
    int col = n0 + nt * 16 + coln;
    float bs = bias1[col] + bias2[col];
    #pragma unroll
    for (int reg = 0; reg < 4; ++reg)
      C[(size_t)(m0 + w * 16 + quad * 4 + reg) * 1024 + col] = acc[nt][reg] + bs;
  }
}

// ---------------- MFMA LSTM recurrence: R0's verified quad protocol with
// vmcnt-queue hygiene ONLY (no protocol change, no spin change):
//  (1) G loads issue POST-spin (acc=0 init; act adds gv) -- they no longer sit
//      in the vmem queue ahead of the spin's poll drains. sched_barrier(0)
//      pins them below the spin loop.
//  (2) Hout stores defer one iteration (written post-spin next step, epilogue
//      for the last) -- fully retired before any spin drains them.
//  (3) Flag stores issue first in the publish phase (earliest visibility).
__global__ __launch_bounds__(256, 1) void k_lstm2(
    const float* __restrict__ Gf, const float* __restrict__ Gb,
    const float* __restrict__ Whf, const float* __restrict__ Whb,
    unsigned* __restrict__ hbuf,               // [256][2][2][16][128] uint (encoded)
    unsigned short* __restrict__ Hout)         // [S][32][512] bf16
{
  __shared__ __align__(16) unsigned hx[2 * HXW];
  const int wg  = blockIdx.x;
  const int dir = wg >> 3, n = (wg >> 1) & 3, bh = wg & 1;
  const float* __restrict__ G  = dir ? Gb : Gf;
  const float* __restrict__ Wh = dir ? Whb : Whf;
  const int tid  = threadIdx.x;
  const int w    = tid >> 6;
  const int lane = tid & 63;
  const int quad = lane >> 4, coln = lane & 15;

  bf16x8 Wr[32];
  #pragma unroll
  for (int ks = 0; ks < 8; ++ks){
    #pragma unroll
    for (int gt = 0; gt < 4; ++gt){
      const float* wp = Wh + (size_t)(gt * 256 + (n << 6) + (w << 4) + coln) * 256
                        + ks * 32 + quad * 8;
      float4 a = *(const float4*)wp;
      float4 b = *(const float4*)(wp + 4);
      union { unsigned u[4]; bf16x8 v; } tu;
      tu.u[0] = f2bf(a.x) | (f2bf(a.y) << 16);
      tu.u[1] = f2bf(a.z) | (f2bf(a.w) << 16);
      tu.u[2] = f2bf(b.x) | (f2bf(b.y) << 16);
      tu.u[3] = f2bf(b.z) | (f2bf(b.w) << 16);
      Wr[ks * 4 + gt] = tu.v;
    }
  }

  const int gu  = (n << 6) + (w << 4) + coln;
  const int mrw = quad << 2;

  float c0 = 0.f, c1 = 0.f, c2 = 0.f, c3 = 0.f;
  unsigned prevH[4];
  int prevS = -1;

  for (int t = 0; t < 256; ++t){
    int s = dir ? (255 - t) : t;
    unsigned* hxr = &hx[(t & 1) * HXW];
    float gv[4][4];
    f32x4 acc[4];

    if (t > 0){
      // ---- spin: byte-identical to R0 ----
      const unsigned* hb = hbuf + (((size_t)(t - 1) * 2 + dir) * 2 + bh) * 2048;
      int row = tid >> 4, kk = tid & 15;
      int n1 = (n + 1) & 3, n2 = (n + 2) & 3, n3 = (n + 3) & 3;
      const unsigned long long* p1 =
          (const unsigned long long*)(hb + row * 128 + n1 * 32 + kk * 2);
      const unsigned long long* p2 =
          (const unsigned long long*)(hb + row * 128 + n2 * 32 + kk * 2);
      const unsigned long long* p3 =
          (const unsigned long long*)(hb + row * 128 + n3 * 32 + kk * 2);
      unsigned long long v1, v2, v3;
      do {
        v1 = __hip_atomic_load(p1, __ATOMIC_RELAXED, __HIP_MEMORY_SCOPE_AGENT);
        v2 = __hip_atomic_load(p2, __ATOMIC_RELAXED, __HIP_MEMORY_SCOPE_AGENT);
        v3 = __hip_atomic_load(p3, __ATOMIC_RELAXED, __HIP_MEMORY_SCOPE_AGENT);
      } while (!(hval_ok(v1) && hval_ok(v2) && hval_ok(v3)));
      __builtin_amdgcn_sched_barrier(0);   // keep G loads BELOW the spin

      // ---- post-spin: issue this step's G loads (hidden under MFMA phase)
      #pragma unroll
      for (int gt = 0; gt < 4; ++gt){
        const float* gp = G + (size_t)(s * 32 + bh * 16 + mrw) * 1024 + gt * 256 + gu;
        gv[gt][0] = gp[0]; gv[gt][1] = gp[1024];
        gv[gt][2] = gp[2048]; gv[gt][3] = gp[3072];
      }
      // ---- deferred Hout from previous step (retired before next spin)
      #pragma unroll
      for (int reg = 0; reg < 4; ++reg)
        Hout[(size_t)(prevS * 32 + bh * 16 + mrw + reg) * 512 + dir * 256 + gu] =
            (unsigned short)prevH[reg];

      hxr[row * 132 + n1 * 32 + kk * 2]     = (unsigned)v1 & 0xBFFFBFFFu;
      hxr[row * 132 + n1 * 32 + kk * 2 + 1] = (unsigned)(v1 >> 32) & 0xBFFFBFFFu;
      hxr[row * 132 + n2 * 32 + kk * 2]     = (unsigned)v2 & 0xBFFFBFFFu;
      hxr[row * 132 + n2 * 32 + kk * 2 + 1] = (unsigned)(v2 >> 32) & 0xBFFFBFFFu;
      hxr[row * 132 + n3 * 32 + kk * 2]     = (unsigned)v3 & 0xBFFFBFFFu;
      hxr[row * 132 + n3 * 32 + kk * 2 + 1] = (unsigned)(v3 >> 32) & 0xBFFFBFFFu;
      __syncthreads();
      #pragma unroll
      for (int gt = 0; gt < 4; ++gt){
        acc[gt][0] = 0.f; acc[gt][1] = 0.f; acc[gt][2] = 0.f; acc[gt][3] = 0.f;
      }
      #pragma unroll
      for (int ks = 0; ks < 8; ++ks){
        union { uint4 q; bf16x8 v; } tu;
        tu.q = *(const uint4*)&hxr[coln * 132 + ks * 16 + quad * 4];
        #pragma unroll
        for (int gt = 0; gt < 4; ++gt)
          acc[gt] = __builtin_amdgcn_mfma_f32_16x16x32_bf16(tu.v, Wr[ks * 4 + gt],
                                                            acc[gt], 0, 0, 0);
      }
    } else {
      #pragma unroll
      for (int gt = 0; gt < 4; ++gt){
        const float* gp = G + (size_t)(s * 32 + bh * 16 + mrw) * 1024 + gt * 256 + gu;
        gv[gt][0] = gp[0]; gv[gt][1] = gp[1024];
        gv[gt][2] = gp[2048]; gv[gt][3] = gp[3072];
      }
      #pragma unroll
      for (int gt = 0; gt < 4; ++gt){
        acc[gt][0] = 0.f; acc[gt][1] = 0.f; acc[gt][2] = 0.f; acc[gt][3] = 0.f;
      }
    }

    unsigned* hxw = &hx[((t + 1) & 1) * HXW];
    unsigned* hw  = hbuf + (((size_t)t * 2 + dir) * 2 + bh) * 2048;
    float cc[4] = {c0, c1, c2, c3};
    unsigned hbv[4], pr[4];
    #pragma unroll
    for (int reg = 0; reg < 4; ++reg){
      float gi = sigf(acc[0][reg] + gv[0][reg]);
      float gf = sigf(acc[1][reg] + gv[1][reg]);
      float gg = thf (acc[2][reg] + gv[2][reg]);
      float go = sigf(acc[3][reg] + gv[3][reg]);
      float cv = gf * cc[reg] + gi * gg;
      cc[reg] = cv;
      float hv = go * thf(cv);
      hbv[reg] = f2bf(hv);
      unsigned other = (unsigned)__shfl_xor((int)hbv[reg], 1);
      pr[reg] = hbv[reg] | (other << 16);
    }
    if (!(coln & 1)){
      if (t < 255){
        #pragma unroll
        for (int reg = 0; reg < 4; ++reg)            // flags first: earliest visibility
          __hip_atomic_store(hw + (mrw + reg) * 128 + (gu >> 1),
                             pr[reg] | 0x40004000u,
                             __ATOMIC_RELAXED, __HIP_MEMORY_SCOPE_AGENT);
      }
      #pragma unroll
      for (int reg = 0; reg < 4; ++reg)
        hxw[(mrw + reg) * 132 + (gu >> 1)] = pr[reg];
    }
    #pragma unroll
    for (int reg = 0; reg < 4; ++reg) prevH[reg] = hbv[reg];
    prevS = s;
    c0 = cc[0]; c1 = cc[1]; c2 = cc[2]; c3 = cc[3];
  }
  // epilogue: Hout for the final step
  #pragma unroll
  for (int reg = 0; reg < 4; ++reg)
    Hout[(size_t)(prevS * 32 + bh * 16 + mrw + reg) * 512 + dir * 256 + gu] =
        (unsigned short)prevH[reg];
}

// ---------------- FC via MFMA: em[8192][32] = h1[8192][512] @ fcw[32][512]^T + fb
// Fragment pattern copied verbatim from the verified k_gemm_bf2.
__global__ __launch_bounds__(256) void k_fc(const unsigned short* __restrict__ h1,
                                            const unsigned short* __restrict__ fw,
                                            const float* __restrict__ fb,
                                            float* __restrict__ em){
  __shared__ __align__(16) unsigned Bs[32 * 260];   // 32 rows x 256 uints (+4 pad)
  const int tid = threadIdx.x;
  const int w = tid >> 6, lane = tid & 63;
  const int quad = lane >> 4, coln = lane & 15;
  const int m0 = blockIdx.x * 64;

  for (int i = tid; i < 2048; i += 256){            // 2048 uint4 = whole fcw
    int r = i >> 6, part = i & 63;
    *(uint4*)&Bs[r * 260 + part * 4] = *(const uint4*)(fw + r * 512 + part * 8);
  }
  __syncthreads();

  f32x4 acc[2];
  acc[0][0]=0.f; acc[0][1]=0.f; acc[0][2]=0.f; acc[0][3]=0.f;
  acc[1][0]=0.f; acc[1][1]=0.f; acc[1][2]=0.f; acc[1][3]=0.f;
  const unsigned short* arow = h1 + (size_t)(m0 + w * 16 + coln) * 512;
  #pragma unroll
  for (int ks = 0; ks < 16; ++ks){
    union { uint4 q; bf16x8 v; } au;
    au.q = *(const uint4*)(arow + ks * 32 + quad * 8);
    #pragma unroll
    for (int nt = 0; nt < 2; ++nt){
      union { uint4 q; bf16x8 v; } bu;
      bu.q = *(const uint4*)&Bs[(nt * 16 + coln) * 260 + ks * 16 + quad * 4];
      acc[nt] = __builtin_amdgcn_mfma_f32_16x16x32_bf16(au.v, bu.v, acc[nt], 0, 0, 0);
    }
  }
  #pragma unroll
  for (int nt = 0; nt < 2; ++nt){
    int col = nt * 16 + coln;
    float bias = fb[col];
    #pragma unroll
    for (int reg = 0; reg < 4; ++reg)
      em[(size_t)(m0 + w * 16 + quad * 4 + reg) * 32 + col] = acc[nt][reg] + bias;
  }
}

// ---------------- CRF: blocks 0..31 viterbi, 32..63 loss
__global__ __launch_bounds__(64) void k_crf(const float* __restrict__ em,
                                            const int* __restrict__ tags,
                                            const float* __restrict__ start,
                                            const float* __restrict__ trans,
                                            const float* __restrict__ endv,
                                            int* __restrict__ path,
                                            float* __restrict__ lossb){
  __shared__ float tr[1024];
  __shared__ float sc[32], sc2[32];
  __shared__ unsigned char bp[255][32];
  int b = blockIdx.x & 31, mode = blockIdx.x >> 5;
  int t = threadIdx.x;
  for (int i = t; i < 1024; i += 64) tr[i] = trans[i];
  if (t < 32) sc[t] = start[t] + em[b * 32 + t];
  __syncthreads();
  if (mode == 0){
    for (int s = 1; s < 256; ++s){
      if (t < 32){
        float best = -1e30f; int bi = 0;
        for (int p = 0; p < 32; ++p){
          float v = sc[p] + tr[p * 32 + t];
          if (v > best){ best = v; bi = p; }
        }
        sc2[t] = best + em[(s * 32 + b) * 32 + t];
        bp[s - 1][t] = (unsigned char)bi;
      }
      __syncthreads();
      if (t < 32) sc[t] = sc2[t];
      __syncthreads();
    }
    if (t == 0){
      float best = -1e30f; int bi = 0;
      for (int p = 0; p < 32; ++p){
        float v = sc[p] + endv[p];
        if (v > best){ best = v; bi = p; }
      }
      int cur = bi;
      path[255 * 32 + b] = cur;
      for (int s = 254; s >= 0; --s){
        cur = bp[s][cur];
        path[s * 32 + b] = cur;
      }
    }
  } else {
    for (int s = 1; s < 256; ++s){
      if (t < 32){
        float m = -1e30f;
        for (int p = 0; p < 32; ++p){ float v = sc[p] + tr[p * 32 + t]; m = fmaxf(m, v); }
        float ss = 0.0f;
        for (int p = 0; p < 32; ++p){ ss += __expf(sc[p] + tr[p * 32 + t] - m); }
        sc2[t] = m + __logf(ss) + em[(s * 32 + b) * 32 + t];
      }
      __syncthreads();
      if (t < 32) sc[t] = sc2[t];
      __syncthreads();
    }
    float nsum = 0.0f;
    for (int s = t; s < 256; s += 64){
      int tg = tags[s * 32 + b];
      nsum += em[(s * 32 + b) * 32 + tg];
      if (s == 0) nsum += start[tg];
      else        nsum += tr[tags[(s - 1) * 32 + b] * 32 + tg];
      if (s == 255) nsum += endv[tg];
    }
    #pragma unroll
    for (int off = 32; off >= 1; off >>= 1) nsum += __shfl_down(nsum, off);
    if (t == 0){
      float m = -1e30f;
      for (int p = 0; p < 32; ++p) m = fmaxf(m, sc[p] + endv[p]);
      float ss = 0.0f;
      for (int p = 0; p < 32; ++p) ss += __expf(sc[p] + endv[p] - m);
      lossb[b] = m + __logf(ss) - nsum;
    }
  }
}

// Sum per-batch losses; write as FLOAT (d_out read back as float32).
__global__ __launch_bounds__(64) void k_final(const float* __restrict__ lossb,
                                              float* __restrict__ outp){
  float v = (threadIdx.x < 32) ? lossb[threadIdx.x] : 0.0f;
  #pragma unroll
  for (int off = 32; off >= 1; off >>= 1) v += __shfl_down(v, off);
  if (threadIdx.x == 0) outp[0] = v;
}

extern "C" void kernel_launch(void* const* d_in, const int* in_sizes, int n_in,
                              void* d_out, int out_size, void* d_ws, size_t ws_size,
                              hipStream_t stream){
  const int*   words  = (const int*)d_in[0];
  const int*   tags   = (const int*)d_in[2];
  const float* emb    = (const float*)d_in[3];
  const float* fcw    = (const float*)d_in[4];
  const float* fcb    = (const float*)d_in[5];
  const float* cstart = (const float*)d_in[6];
  const float* cend   = (const float*)d_in[7];
  const float* ctrans = (const float*)d_in[8];
  const float* w_ih[4] = {(const float*)d_in[9],  (const float*)d_in[13],
                          (const float*)d_in[17], (const float*)d_in[21]};
  const float* w_hh[4] = {(const float*)d_in[10], (const float*)d_in[14],
                          (const float*)d_in[18], (const float*)d_in[22]};
  const float* b_ih[4] = {(const float*)d_in[11], (const float*)d_in[15],
                          (const float*)d_in[19], (const float*)d_in[23]};
  const float* b_hh[4] = {(const float*)d_in[12], (const float*)d_in[16],
                          (const float*)d_in[20], (const float*)d_in[24]};

  char* base = (char*)d_ws;
  unsigned short* x    = (unsigned short*)base;                 // 5,242,880 B
  float* Gf            = (float*)(base + 5242880);              // 33,554,432 B
  float* Gb            = (float*)(base + 38797312);             // 33,554,432 B
  unsigned short* h0   = (unsigned short*)(base + 72351744);    // 8,388,608 B
  unsigned short* h1   = (unsigned short*)(base + 80740352);    // 8,388,608 B
  unsigned short* wb0f = (unsigned short*)(base + 89128960);    // 655,360 B
  unsigned short* wb0b = (unsigned short*)(base + 89784320);    // 655,360 B
  unsigned short* wb1f = (unsigned short*)(base + 90439680);    // 1,048,576 B
  unsigned short* wb1b = (unsigned short*)(base + 91488256);    // 1,048,576 B
  unsigned short* fcwb = (unsigned short*)(base + 92536832);    // 32,768 B
  float* lossb         = (float*)(base + 92569600);             // 128 B
  float* em            = Gf;                        // overlay: Gf dead after L1 lstm
  unsigned* hbuf0 = (unsigned*)h1;   // L0 exchange (zeroed in k_prep)
  unsigned* hbuf1 = (unsigned*)h0;   // L1 exchange (L0 bf16 |h|<=1 => bit14 clear)

  k_prep<<<8192, 320, 0, stream>>>(words, emb, x, hbuf0);
  k_packw<<<4128, 256, 0, stream>>>(w_ih[0], w_ih[1], w_ih[2], w_ih[3], fcw,
                                    wb0f, wb0b, wb1f, wb1b, fcwb);

  // layer 0 input projections (K padded to 320), both dirs in one launch
  k_gemm_bf2<<<dim3(8, 128, 2), 256, 0, stream>>>(x, 320, 10, wb0f, wb0b,
                                                  b_ih[0], b_hh[0], b_ih[1], b_hh[1],
                                                  Gf, Gb);
  k_lstm2<<<16, 256, 0, stream>>>(Gf, Gb, w_hh[0], w_hh[1], hbuf0, h0);

  // layer 1 input projections (K=512)
  k_gemm_bf2<<<dim3(8, 128, 2), 256, 0, stream>>>(h0, 512, 16, wb1f, wb1b,
                                                  b_ih[2], b_hh[2], b_ih[3], b_hh[3],
                                                  Gf, Gb);
  k_lstm2<<<16, 256, 0, stream>>>(Gf, Gb, w_hh[2], w_hh[3], hbuf1, h1);

  k_fc<<<128, 256, 0, stream>>>(h1, fcwb, fcb, em);

  k_crf<<<64, 64, 0, stream>>>(em, tags, cstart, ctrans, cend, (int*)d_out, lossb);
  k_final<<<1, 64, 0, stream>>>(lossb, ((float*)d_out) + (out_size - 1));
}

// Round 10
// 1412.789 us; speedup vs baseline: 2.6865x; 1.0528x over previous
//
#include <hip/hip_runtime.h>
#include <stdint.h>

// Problem dims
#define S_ 256
#define B_ 32
#define H_ 256
#define G4_ 1024   // 4*H
#define HXW (16*132)

typedef short bf16x8 __attribute__((ext_vector_type(8)));
typedef float f32x4  __attribute__((ext_vector_type(4)));

__device__ __forceinline__ unsigned f2bf(float f){
  unsigned u = __float_as_uint(f);
  return (u + 0x7fffu + ((u >> 16) & 1u)) >> 16;   // RNE to bf16
}
__device__ __forceinline__ float bfl(unsigned u){ return __uint_as_float(u << 16); }
__device__ __forceinline__ float bfh(unsigned u){ return __uint_as_float(u & 0xffff0000u); }
__device__ __forceinline__ float sigf(float x){ return 1.0f / (1.0f + __expf(-x)); }
__device__ __forceinline__ float thf(float x){
  x = fminf(fmaxf(x, -15.0f), 15.0f);
  float e = __expf(2.0f * x);
  return (e - 1.0f) / (e + 1.0f);
}

// valid iff both 16b halves have bit14 set (|h|<=1 => raw bf16 bit14 clear)
__device__ __forceinline__ int hval_ok(unsigned long long v){
  return (((unsigned)v & (unsigned)(v >> 32)) & 0x40004000u) == 0x40004000u;
}

// ---------------- merged prep: blocks 0..8191 embedding gather + hbuf0 zero;
// blocks 8192..12319 weight pack (former k_packw grid of 4128)
__global__ __launch_bounds__(320) void k_prep(
    const int* __restrict__ words, const float* __restrict__ emb,
    unsigned short* __restrict__ x, unsigned* __restrict__ hbuf0,
    const float* __restrict__ w0f, const float* __restrict__ w0b,
    const float* __restrict__ w1f, const float* __restrict__ w1b,
    const float* __restrict__ fw,
    unsigned short* __restrict__ wb0f, unsigned short* __restrict__ wb0b,
    unsigned short* __restrict__ wb1f, unsigned short* __restrict__ wb1b,
    unsigned short* __restrict__ fcwb){
  int blk = blockIdx.x, tid = threadIdx.x;
  if (blk < 8192){
    int row = blk;                 // s*32+b
    int e = tid;                   // 0..319
    int w = words[row];
    x[row * 320 + e] = (e < 300) ? (unsigned short)f2bf(emb[w * 300 + e]) : 0;
    if (e < 256) hbuf0[row * 256 + e] = 0;   // 8192*256 uints = 8 MB
    return;
  }
  int r = blk - 8192;              // 0..4127
  if (r < 2048){
    int rr = r & 1023;
    const float* src = (r < 1024) ? w0f : w0b;
    unsigned short* dst = (r < 1024) ? wb0f : wb0b;
    for (int e = tid; e < 320; e += 320)
      dst[rr * 320 + e] = (e < 300) ? (unsigned short)f2bf(src[rr * 300 + e]) : 0;
  } else if (r < 4096){
    int rr = r & 1023;
    const float* src = (r < 3072) ? w1f : w1b;
    unsigned short* dst = (r < 3072) ? wb1f : wb1b;
    for (int e = tid; e < 512; e += 320)
      dst[rr * 512 + e] = (unsigned short)f2bf(src[rr * 512 + e]);
  } else {
    int rr = r - 4096;
    for (int e = tid; e < 512; e += 320)
      fcwb[rr * 512 + e] = (unsigned short)f2bf(fw[rr * 512 + e]);
  }
}

// ---------------- bf16 MFMA GEMM (both dirs via blockIdx.z) -- R0 verified
__global__ __launch_bounds__(256) void k_gemm_bf2(
    const unsigned short* __restrict__ A, int lda, int nSteps,
    const unsigned short* __restrict__ Bf, const unsigned short* __restrict__ Bb,
    const float* __restrict__ b1f, const float* __restrict__ b2f,
    const float* __restrict__ b1b, const float* __restrict__ b2b,
    float* __restrict__ Cf, float* __restrict__ Cb){
  const int z = blockIdx.z;
  const unsigned short* __restrict__ B = z ? Bb : Bf;
  const float* __restrict__ bias1 = z ? b1b : b1f;
  const float* __restrict__ bias2 = z ? b2b : b2f;
  float* __restrict__ C = z ? Cb : Cf;

  __shared__ __align__(16) unsigned As[64 * 20];
  __shared__ __align__(16) unsigned Bs[128 * 20];
  const int tid = threadIdx.x;
  const int w = tid >> 6, lane = tid & 63;
  const int quad = lane >> 4, coln = lane & 15;
  const int m0 = blockIdx.y * 64, n0 = blockIdx.x * 128;

  f32x4 acc[8];
  #pragma unroll
  for (int i = 0; i < 8; ++i){ acc[i][0]=0.f; acc[i][1]=0.f; acc[i][2]=0.f; acc[i][3]=0.f; }

  for (int kt = 0; kt < nSteps; ++kt){
    int k0 = kt * 32;
    __syncthreads();
    {
      int row = tid >> 2, part = tid & 3;
      *(uint4*)&As[row * 20 + part * 4] =
          *(const uint4*)(A + (size_t)(m0 + row) * lda + k0 + part * 8);
    }
    #pragma unroll
    for (int i = 0; i < 2; ++i){
      int idx = tid + 256 * i;
      int row = idx >> 2, part = idx & 3;
      *(uint4*)&Bs[row * 20 + part * 4] =
          *(const uint4*)(B + (size_t)(n0 + row) * lda + k0 + part * 8);
    }
    __syncthreads();
    union { uint4 q; bf16x8 v; } au;
    au.q = *(const uint4*)&As[(w * 16 + coln) * 20 + quad * 4];
    #pragma unroll
    for (int nt = 0; nt < 8; ++nt){
      union { uint4 q; bf16x8 v; } bu;
      bu.q = *(const uint4*)&Bs[(nt * 16 + coln) * 20 + quad * 4];
      acc[nt] = __builtin_amdgcn_mfma_f32_16x16x32_bf16(au.v, bu.v, acc[nt], 0, 0, 0);
    }
  }
  #pragma unroll
  for (int nt = 0; nt < 8; ++nt){
    int col = n0 + nt * 16 + coln;
    float bs = bias1[col] + bias2[col];
    #pragma unroll
    for (int reg = 0; reg < 4; ++reg)
      C[(size_t)(m0 + w * 16 + quad * 4 + reg) * 1024 + col] = acc[nt][reg] + bs;
  }
}

// ---------------- MFMA LSTM recurrence, data-as-flag exchange (agent scope).
// BYTE-EXACT the verified R0 kernel (measured 520 us): protocol, spin, LDS
// layout, publish order all unchanged. Nine rounds of variants (direct-reg
// polling, fast rings, pipelined vmcnt spins, queue hygiene, single-CU
// residency) all measured equal or worse -- this is the protocol floor.
__global__ __launch_bounds__(256, 1) void k_lstm2(
    const float* __restrict__ Gf, const float* __restrict__ Gb,
    const float* __restrict__ Whf, const float* __restrict__ Whb,
    unsigned* __restrict__ hbuf,               // [256][2][2][16][128] uint (encoded)
    unsigned short* __restrict__ Hout)         // [S][32][512] bf16
{
  __shared__ __align__(16) unsigned hx[2 * HXW];
  const int wg  = blockIdx.x;
  const int dir = wg >> 3, n = (wg >> 1) & 3, bh = wg & 1;
  const float* __restrict__ G  = dir ? Gb : Gf;
  const float* __restrict__ Wh = dir ? Whb : Whf;
  const int tid  = threadIdx.x;
  const int w    = tid >> 6;
  const int lane = tid & 63;
  const int quad = lane >> 4, coln = lane & 15;

  bf16x8 Wr[32];
  #pragma unroll
  for (int ks = 0; ks < 8; ++ks){
    #pragma unroll
    for (int gt = 0; gt < 4; ++gt){
      const float* wp = Wh + (size_t)(gt * 256 + (n << 6) + (w << 4) + coln) * 256
                        + ks * 32 + quad * 8;
      float4 a = *(const float4*)wp;
      float4 b = *(const float4*)(wp + 4);
      union { unsigned u[4]; bf16x8 v; } tu;
      tu.u[0] = f2bf(a.x) | (f2bf(a.y) << 16);
      tu.u[1] = f2bf(a.z) | (f2bf(a.w) << 16);
      tu.u[2] = f2bf(b.x) | (f2bf(b.y) << 16);
      tu.u[3] = f2bf(b.z) | (f2bf(b.w) << 16);
      Wr[ks * 4 + gt] = tu.v;
    }
  }

  const int gu  = (n << 6) + (w << 4) + coln;
  const int mrw = quad << 2;

  float c0 = 0.f, c1 = 0.f, c2 = 0.f, c3 = 0.f;

  for (int t = 0; t < 256; ++t){
    int s = dir ? (255 - t) : t;
    f32x4 acc[4];
    #pragma unroll
    for (int gt = 0; gt < 4; ++gt){
      const float* gp = G + (size_t)(s * 32 + bh * 16 + mrw) * 1024 + gt * 256 + gu;
      f32x4 a;
      a[0] = gp[0]; a[1] = gp[1024]; a[2] = gp[2048]; a[3] = gp[3072];
      acc[gt] = a;
    }
    unsigned* hxr = &hx[(t & 1) * HXW];
    if (t > 0){
      const unsigned* hb = hbuf + (((size_t)(t - 1) * 2 + dir) * 2 + bh) * 2048;
      int row = tid >> 4, kk = tid & 15;
      int n1 = (n + 1) & 3, n2 = (n + 2) & 3, n3 = (n + 3) & 3;
      const unsigned long long* p1 =
          (const unsigned long long*)(hb + row * 128 + n1 * 32 + kk * 2);
      const unsigned long long* p2 =
          (const unsigned long long*)(hb + row * 128 + n2 * 32 + kk * 2);
      const unsigned long long* p3 =
          (const unsigned long long*)(hb + row * 128 + n3 * 32 + kk * 2);
      unsigned long long v1, v2, v3;
      do {
        v1 = __hip_atomic_load(p1, __ATOMIC_RELAXED, __HIP_MEMORY_SCOPE_AGENT);
        v2 = __hip_atomic_load(p2, __ATOMIC_RELAXED, __HIP_MEMORY_SCOPE_AGENT);
        v3 = __hip_atomic_load(p3, __ATOMIC_RELAXED, __HIP_MEMORY_SCOPE_AGENT);
      } while (!(hval_ok(v1) && hval_ok(v2) && hval_ok(v3)));
      hxr[row * 132 + n1 * 32 + kk * 2]     = (unsigned)v1 & 0xBFFFBFFFu;
      hxr[row * 132 + n1 * 32 + kk * 2 + 1] = (unsigned)(v1 >> 32) & 0xBFFFBFFFu;
      hxr[row * 132 + n2 * 32 + kk * 2]     = (unsigned)v2 & 0xBFFFBFFFu;
      hxr[row * 132 + n2 * 32 + kk * 2 + 1] = (unsigned)(v2 >> 32) & 0xBFFFBFFFu;
      hxr[row * 132 + n3 * 32 + kk * 2]     = (unsigned)v3 & 0xBFFFBFFFu;
      hxr[row * 132 + n3 * 32 + kk * 2 + 1] = (unsigned)(v3 >> 32) & 0xBFFFBFFFu;
      __syncthreads();
      #pragma unroll
      for (int ks = 0; ks < 8; ++ks){
        union { uint4 q; bf16x8 v; } tu;
        tu.q = *(const uint4*)&hxr[coln * 132 + ks * 16 + quad * 4];
        #pragma unroll
        for (int gt = 0; gt < 4; ++gt)
          acc[gt] = __builtin_amdgcn_mfma_f32_16x16x32_bf16(tu.v, Wr[ks * 4 + gt],
                                                            acc[gt], 0, 0, 0);
      }
    }
    unsigned* hxw = &hx[((t + 1) & 1) * HXW];
    unsigned* hw  = hbuf + (((size_t)t * 2 + dir) * 2 + bh) * 2048;
    float cc[4] = {c0, c1, c2, c3};
    #pragma unroll
    for (int reg = 0; reg < 4; ++reg){
      float gi = sigf(acc[0][reg]);
      float gf = sigf(acc[1][reg]);
      float gg = thf (acc[2][reg]);
      float go = sigf(acc[3][reg]);
      float cv = gf * cc[reg] + gi * gg;
      cc[reg] = cv;
      float hv = go * thf(cv);
      unsigned hb16 = f2bf(hv);
      unsigned other = (unsigned)__shfl_xor((int)hb16, 1);
      if (!(coln & 1)){
        unsigned pair = hb16 | (other << 16);
        hxw[(mrw + reg) * 132 + (gu >> 1)] = pair;
        if (t < 255)
          __hip_atomic_store(hw + (mrw + reg) * 128 + (gu >> 1),
                             pair | 0x40004000u,
                             __ATOMIC_RELAXED, __HIP_MEMORY_SCOPE_AGENT);
      }
      Hout[(size_t)(s * 32 + bh * 16 + mrw + reg) * 512 + dir * 256 + gu] =
          (unsigned short)hb16;
    }
    c0 = cc[0]; c1 = cc[1]; c2 = cc[2]; c3 = cc[3];
  }
}

// ---------------- FC via MFMA: em[8192][32] = h1[8192][512] @ fcw[32][512]^T + fb
// (verified in R9)
__global__ __launch_bounds__(256) void k_fc(const unsigned short* __restrict__ h1,
                                            const unsigned short* __restrict__ fw,
                                            const float* __restrict__ fb,
                                            float* __restrict__ em){
  __shared__ __align__(16) unsigned Bs[32 * 260];   // 32 rows x 256 uints (+4 pad)
  const int tid = threadIdx.x;
  const int w = tid >> 6, lane = tid & 63;
  const int quad = lane >> 4, coln = lane & 15;
  const int m0 = blockIdx.x * 64;

  for (int i = tid; i < 2048; i += 256){            // 2048 uint4 = whole fcw
    int r = i >> 6, part = i & 63;
    *(uint4*)&Bs[r * 260 + part * 4] = *(const uint4*)(fw + r * 512 + part * 8);
  }
  __syncthreads();

  f32x4 acc[2];
  acc[0][0]=0.f; acc[0][1]=0.f; acc[0][2]=0.f; acc[0][3]=0.f;
  acc[1][0]=0.f; acc[1][1]=0.f; acc[1][2]=0.f; acc[1][3]=0.f;
  const unsigned short* arow = h1 + (size_t)(m0 + w * 16 + coln) * 512;
  #pragma unroll
  for (int ks = 0; ks < 16; ++ks){
    union { uint4 q; bf16x8 v; } au;
    au.q = *(const uint4*)(arow + ks * 32 + quad * 8);
    #pragma unroll
    for (int nt = 0; nt < 2; ++nt){
      union { uint4 q; bf16x8 v; } bu;
      bu.q = *(const uint4*)&Bs[(nt * 16 + coln) * 260 + ks * 16 + quad * 4];
      acc[nt] = __builtin_amdgcn_mfma_f32_16x16x32_bf16(au.v, bu.v, acc[nt], 0, 0, 0);
    }
  }
  #pragma unroll
  for (int nt = 0; nt < 2; ++nt){
    int col = nt * 16 + coln;
    float bias = fb[col];
    #pragma unroll
    for (int reg = 0; reg < 4; ++reg)
      em[(size_t)(m0 + w * 16 + quad * 4 + reg) * 32 + col] = acc[nt][reg] + bias;
  }
}

// ---------------- CRF: blocks 0..31 viterbi, 32..63 loss.
// Inner 32-transition reduction now uses all 64 lanes: lane = (tt, half),
// each half reduces 16 p-values, combined via one __shfl_xor(..., 32).
// First-max tie semantics preserved (strict > on the upper-half candidate).
__global__ __launch_bounds__(64) void k_crf(const float* __restrict__ em,
                                            const int* __restrict__ tags,
                                            const float* __restrict__ start,
                                            const float* __restrict__ trans,
                                            const float* __restrict__ endv,
                                            int* __restrict__ path,
                                            float* __restrict__ lossb){
  __shared__ float tr[1024];
  __shared__ float sc[32], sc2[32];
  __shared__ unsigned char bp[255][32];
  int b = blockIdx.x & 31, mode = blockIdx.x >> 5;
  int t = threadIdx.x;
  int tt = t & 31, half = t >> 5;
  for (int i = t; i < 1024; i += 64) tr[i] = trans[i];
  if (t < 32) sc[t] = start[t] + em[b * 32 + t];
  __syncthreads();
  if (mode == 0){
    for (int s = 1; s < 256; ++s){
      float best = -1e30f; int bi = 0;
      #pragma unroll
      for (int q = 0; q < 16; ++q){
        int p = half * 16 + q;
        float v = sc[p] + tr[p * 32 + tt];
        if (v > best){ best = v; bi = p; }
      }
      float ob = __shfl_xor(best, 32);
      int   oi = __shfl_xor(bi, 32);
      if (half == 0){
        if (ob > best){ best = ob; bi = oi; }   // upper half wins only strictly
        sc2[tt] = best + em[(s * 32 + b) * 32 + tt];
        bp[s - 1][tt] = (unsigned char)bi;
      }
      __syncthreads();
      if (t < 32) sc[t] = sc2[t];
      __syncthreads();
    }
    if (t == 0){
      float best = -1e30f; int bi = 0;
      for (int p = 0; p < 32; ++p){
        float v = sc[p] + endv[p];
        if (v > best){ best = v; bi = p; }
      }
      int cur = bi;
      path[255 * 32 + b] = cur;
      for (int s = 254; s >= 0; --s){
        cur = bp[s][cur];
        path[s * 32 + b] = cur;
      }
    }
  } else {
    for (int s = 1; s < 256; ++s){
      float m = -1e30f;
      #pragma unroll
      for (int q = 0; q < 16; ++q){
        int p = half * 16 + q;
        m = fmaxf(m, sc[p] + tr[p * 32 + tt]);
      }
      float ss = 0.0f;
      #pragma unroll
      for (int q = 0; q < 16; ++q){
        int p = half * 16 + q;
        ss += __expf(sc[p] + tr[p * 32 + tt] - m);
      }
      float om = __shfl_xor(m, 32);
      float os = __shfl_xor(ss, 32);
      if (half == 0){
        float M = fmaxf(m, om);
        float SS = ss * __expf(m - M) + os * __expf(om - M);
        sc2[tt] = M + __logf(SS) + em[(s * 32 + b) * 32 + tt];
      }
      __syncthreads();
      if (t < 32) sc[t] = sc2[t];
      __syncthreads();
    }
    float nsum = 0.0f;
    for (int s = t; s < 256; s += 64){
      int tg = tags[s * 32 + b];
      nsum += em[(s * 32 + b) * 32 + tg];
      if (s == 0) nsum += start[tg];
      else        nsum += tr[tags[(s - 1) * 32 + b] * 32 + tg];
      if (s == 255) nsum += endv[tg];
    }
    #pragma unroll
    for (int off = 32; off >= 1; off >>= 1) nsum += __shfl_down(nsum, off);
    if (t == 0){
      float m = -1e30f;
      for (int p = 0; p < 32; ++p) m = fmaxf(m, sc[p] + endv[p]);
      float ss = 0.0f;
      for (int p = 0; p < 32; ++p) ss += __expf(sc[p] + endv[p] - m);
      lossb[b] = m + __logf(ss) - nsum;
    }
  }
}

// Sum per-batch losses; write as FLOAT (d_out read back as float32).
__global__ __launch_bounds__(64) void k_final(const float* __restrict__ lossb,
                                              float* __restrict__ outp){
  float v = (threadIdx.x < 32) ? lossb[threadIdx.x] : 0.0f;
  #pragma unroll
  for (int off = 32; off >= 1; off >>= 1) v += __shfl_down(v, off);
  if (threadIdx.x == 0) outp[0] = v;
}

extern "C" void kernel_launch(void* const* d_in, const int* in_sizes, int n_in,
                              void* d_out, int out_size, void* d_ws, size_t ws_size,
                              hipStream_t stream){
  const int*   words  = (const int*)d_in[0];
  const int*   tags   = (const int*)d_in[2];
  const float* emb    = (const float*)d_in[3];
  const float* fcw    = (const float*)d_in[4];
  const float* fcb    = (const float*)d_in[5];
  const float* cstart = (const float*)d_in[6];
  const float* cend   = (const float*)d_in[7];
  const float* ctrans = (const float*)d_in[8];
  const float* w_ih[4] = {(const float*)d_in[9],  (const float*)d_in[13],
                          (const float*)d_in[17], (const float*)d_in[21]};
  const float* w_hh[4] = {(const float*)d_in[10], (const float*)d_in[14],
                          (const float*)d_in[18], (const float*)d_in[22]};
  const float* b_ih[4] = {(const float*)d_in[11], (const float*)d_in[15],
                          (const float*)d_in[19], (const float*)d_in[23]};
  const float* b_hh[4] = {(const float*)d_in[12], (const float*)d_in[16],
                          (const float*)d_in[20], (const float*)d_in[24]};

  char* base = (char*)d_ws;
  unsigned short* x    = (unsigned short*)base;                 // 5,242,880 B
  float* Gf            = (float*)(base + 5242880);              // 33,554,432 B
  float* Gb            = (float*)(base + 38797312);             // 33,554,432 B
  unsigned short* h0   = (unsigned short*)(base + 72351744);    // 8,388,608 B
  unsigned short* h1   = (unsigned short*)(base + 80740352);    // 8,388,608 B
  unsigned short* wb0f = (unsigned short*)(base + 89128960);    // 655,360 B
  unsigned short* wb0b = (unsigned short*)(base + 89784320);    // 655,360 B
  unsigned short* wb1f = (unsigned short*)(base + 90439680);    // 1,048,576 B
  unsigned short* wb1b = (unsigned short*)(base + 91488256);    // 1,048,576 B
  unsigned short* fcwb = (unsigned short*)(base + 92536832);    // 32,768 B
  float* lossb         = (float*)(base + 92569600);             // 128 B
  float* em            = Gf;                        // overlay: Gf dead after L1 lstm
  unsigned* hbuf0 = (unsigned*)h1;   // L0 exchange (zeroed in k_prep)
  unsigned* hbuf1 = (unsigned*)h0;   // L1 exchange (L0 bf16 |h|<=1 => bit14 clear)

  k_prep<<<12320, 320, 0, stream>>>(words, emb, x, hbuf0,
                                    w_ih[0], w_ih[1], w_ih[2], w_ih[3], fcw,
                                    wb0f, wb0b, wb1f, wb1b, fcwb);

  // layer 0 input projections (K padded to 320), both dirs in one launch
  k_gemm_bf2<<<dim3(8, 128, 2), 256, 0, stream>>>(x, 320, 10, wb0f, wb0b,
                                                  b_ih[0], b_hh[0], b_ih[1], b_hh[1],
                                                  Gf, Gb);
  k_lstm2<<<16, 256, 0, stream>>>(Gf, Gb, w_hh[0], w_hh[1], hbuf0, h0);

  // layer 1 input projections (K=512)
  k_gemm_bf2<<<dim3(8, 128, 2), 256, 0, stream>>>(h0, 512, 16, wb1f, wb1b,
                                                  b_ih[2], b_hh[2], b_ih[3], b_hh[3],
                                                  Gf, Gb);
  k_lstm2<<<16, 256, 0, stream>>>(Gf, Gb, w_hh[2], w_hh[3], hbuf1, h1);

  k_fc<<<128, 256, 0, stream>>>(h1, fcwb, fcb, em);

  k_crf<<<64, 64, 0, stream>>>(em, tags, cstart, ctrans, cend, (int*)d_out, lossb);
  k_final<<<1, 64, 0, stream>>>(lossb, ((float*)d_out) + (out_size - 1));
}